// Round 2
// baseline (7785.708 us; speedup 1.0000x reference)
//
#include <hip/hip_runtime.h>
#include <hip/hip_bf16.h>

namespace {

constexpr int kN  = 32768;   // nodes
constexpr int kD  = 384;     // features
constexpr int kB  = 32;      // graphs
constexpr int kS  = 1024;    // nodes per graph
constexpr int kH  = 8;       // heads
constexpr int kDH = 48;      // head dim
constexpr int kFF = 768;     // ffn hidden
constexpr int kE  = 524288;  // edges
constexpr int kND = kN * kD; // 12,582,912

// ---------------- edge scatter: agg[dst] += relu(x[src] + edge_attr) -------------
__global__ __launch_bounds__(256) void edge_kernel(
    const float* __restrict__ x, const float* __restrict__ ea,
    const int* __restrict__ ei, float* __restrict__ agg)
{
    unsigned gid = blockIdx.x * 256u + threadIdx.x;     // kE*96 threads, 4 feats each
    unsigned e = gid / 96u, d4 = (gid % 96u) * 4u;
    int src = ei[e], dst = ei[kE + e];
    float4 av = *reinterpret_cast<const float4*>(ea + (size_t)e * kD + d4);
    float4 xv = *reinterpret_cast<const float4*>(x + (size_t)src * kD + d4);
    float* out = agg + (size_t)dst * kD + d4;
    float m[4] = {av.x + xv.x, av.y + xv.y, av.z + xv.z, av.w + xv.w};
#pragma unroll
    for (int i = 0; i < 4; ++i)
        if (m[i] > 0.f) atomicAdd(out + i, m[i]);       // skip zero adds: ~2x fewer atomics
}

// ---------------- elementwise: a += b ------------------------------------------
__global__ __launch_bounds__(256) void addf_kernel(float* __restrict__ a,
                                                   const float* __restrict__ b)
{
    unsigned i = (blockIdx.x * 256u + threadIdx.x) * 4u;
    float4 va = *reinterpret_cast<const float4*>(a + i);
    float4 vb = *reinterpret_cast<const float4*>(b + i);
    va.x += vb.x; va.y += vb.y; va.z += vb.z; va.w += vb.w;
    *reinterpret_cast<float4*>(a + i) = va;
}

// ---------------- tiled GEMM: C = [res +] act(A @ W + bias) ---------------------
// A: M x K f32, W: K x Nw f32 row-major, bias: Nw f32, C: M x Nw f32.
// RES: 0 none, 1 f32 residual (leading dim == Nw).
template<bool RELU, int RES>
__global__ __launch_bounds__(256) void gemm_kernel(
    const float* __restrict__ A, const float* __restrict__ W,
    const float* __restrict__ bias, const float* __restrict__ res,
    float* __restrict__ C, int M, int K, int Nw)
{
    __shared__ float As[64][17];
    __shared__ float Ws[16][65];
    const int tid = threadIdx.x;
    const int tx = tid & 15, ty = tid >> 4;
    const int row0 = blockIdx.y * 64, col0 = blockIdx.x * 64;
    const int lar = tid >> 2, lac = (tid & 3) * 4;   // A-tile loader: 64x16
    const int lwr = tid >> 4, lwc = (tid & 15) * 4;  // W-tile loader: 16x64
    float acc[4][4] = {};
    for (int kt = 0; kt < K; kt += 16) {
        {
            float4 v = *reinterpret_cast<const float4*>(A + (size_t)(row0 + lar) * K + kt + lac);
            As[lar][lac] = v.x; As[lar][lac + 1] = v.y;
            As[lar][lac + 2] = v.z; As[lar][lac + 3] = v.w;
        }
        {
            float4 v = *reinterpret_cast<const float4*>(W + (size_t)(kt + lwr) * Nw + col0 + lwc);
            Ws[lwr][lwc] = v.x; Ws[lwr][lwc + 1] = v.y;
            Ws[lwr][lwc + 2] = v.z; Ws[lwr][lwc + 3] = v.w;
        }
        __syncthreads();
#pragma unroll
        for (int k = 0; k < 16; ++k) {
            float a[4], w[4];
#pragma unroll
            for (int i = 0; i < 4; ++i) a[i] = As[ty * 4 + i][k];
#pragma unroll
            for (int j = 0; j < 4; ++j) w[j] = Ws[k][tx * 4 + j];
#pragma unroll
            for (int i = 0; i < 4; ++i)
#pragma unroll
                for (int j = 0; j < 4; ++j) acc[i][j] = fmaf(a[i], w[j], acc[i][j]);
        }
        __syncthreads();
    }
#pragma unroll
    for (int i = 0; i < 4; ++i) {
        int row = row0 + ty * 4 + i;
#pragma unroll
        for (int j = 0; j < 4; ++j) {
            int col = col0 + tx * 4 + j;
            float v = acc[i][j] + bias[col];
            if constexpr (RES == 1) v += res[(size_t)row * Nw + col];
            if constexpr (RELU) v = fmaxf(v, 0.f);
            C[(size_t)row * Nw + col] = v;
        }
    }
}

// ---------------- flash attention per (b, h, 64-query tile) ----------------------
// q,k,v: (N, D) f32 with head h at columns [h*48, h*48+48). Writes O in-place over
// q's region (each block is the only reader of its own Q rows/columns).
__global__ __launch_bounds__(256) void attn_kernel(
    const float* __restrict__ qf, const float* __restrict__ kf,
    const float* __restrict__ vf, float* __restrict__ of)
{
    __shared__ float Qs[64][49];
    __shared__ float Ks[64][49];
    __shared__ float Vs[64][49];
    __shared__ float St[64][65];
    __shared__ float mrow[64], lrow[64], arow[64];
    const int tid = threadIdx.x;
    const int i0 = blockIdx.x * 64;
    const int bh = blockIdx.y;
    const int b = bh >> 3, h = bh & 7;
    const size_t nb = (size_t)b * kS;
    const int coff = h * kDH;
    if (tid < 64) { mrow[tid] = -1e30f; lrow[tid] = 0.f; }
    for (int idx = tid; idx < 64 * 12; idx += 256) {        // Q tile 64x48
        int r = idx / 12, c4 = (idx % 12) * 4;
        float4 v = *reinterpret_cast<const float4*>(qf + (nb + i0 + r) * kD + coff + c4);
        Qs[r][c4] = v.x; Qs[r][c4 + 1] = v.y; Qs[r][c4 + 2] = v.z; Qs[r][c4 + 3] = v.w;
    }
    const int tx = tid & 15, ty = tid >> 4;        // scores mapping (4x4 per thread)
    const int srow = tid >> 2, str = tid & 3;      // softmax mapping (4 threads/row)
    const int pg = tid / 48, pd = tid % 48;        // PV mapping (tid<192)
    float oacc[16];
#pragma unroll
    for (int i = 0; i < 16; ++i) oacc[i] = 0.f;
    const float scale = 0.14433756729740643f;      // 1/sqrt(48)
    for (int jt = 0; jt < 16; ++jt) {
        int j0 = jt * 64;
        for (int idx = tid; idx < 64 * 12; idx += 256) {    // K,V tiles 64x48
            int r = idx / 12, c4 = (idx % 12) * 4;
            float4 v = *reinterpret_cast<const float4*>(kf + (nb + j0 + r) * kD + coff + c4);
            Ks[r][c4] = v.x; Ks[r][c4 + 1] = v.y; Ks[r][c4 + 2] = v.z; Ks[r][c4 + 3] = v.w;
            float4 w = *reinterpret_cast<const float4*>(vf + (nb + j0 + r) * kD + coff + c4);
            Vs[r][c4] = w.x; Vs[r][c4 + 1] = w.y; Vs[r][c4 + 2] = w.z; Vs[r][c4 + 3] = w.w;
        }
        __syncthreads();
        float acc[4][4] = {};
#pragma unroll 8
        for (int kk = 0; kk < 48; ++kk) {
            float a[4], c[4];
#pragma unroll
            for (int i = 0; i < 4; ++i) a[i] = Qs[ty * 4 + i][kk];
#pragma unroll
            for (int j = 0; j < 4; ++j) c[j] = Ks[tx * 4 + j][kk];
#pragma unroll
            for (int i = 0; i < 4; ++i)
#pragma unroll
                for (int j = 0; j < 4; ++j) acc[i][j] = fmaf(a[i], c[j], acc[i][j]);
        }
#pragma unroll
        for (int i = 0; i < 4; ++i)
#pragma unroll
            for (int j = 0; j < 4; ++j)
                St[ty * 4 + i][tx * 4 + j] = acc[i][j] * scale;
        __syncthreads();
        {   // online softmax: 4 consecutive lanes per row (same wave -> lockstep)
            float mx = -1e30f;
#pragma unroll
            for (int jj = 0; jj < 16; ++jj) mx = fmaxf(mx, St[srow][str * 16 + jj]);
            mx = fmaxf(mx, __shfl_xor(mx, 1));
            mx = fmaxf(mx, __shfl_xor(mx, 2));
            float mold = mrow[srow];
            float mnew = fmaxf(mold, mx);
            float sum = 0.f;
#pragma unroll
            for (int jj = 0; jj < 16; ++jj) {
                float p = __expf(St[srow][str * 16 + jj] - mnew);
                St[srow][str * 16 + jj] = p;
                sum += p;
            }
            sum += __shfl_xor(sum, 1);
            sum += __shfl_xor(sum, 2);
            if (str == 0) {
                float al = __expf(mold - mnew);
                arow[srow] = al;
                lrow[srow] = lrow[srow] * al + sum;
                mrow[srow] = mnew;
            }
        }
        __syncthreads();
        if (tid < 192) {   // PV: O[r][pd] = O*alpha + P @ V
#pragma unroll
            for (int ii = 0; ii < 16; ++ii) {
                int r = pg * 16 + ii;
                float a = oacc[ii] * arow[r];
#pragma unroll 16
                for (int jj = 0; jj < 64; ++jj)
                    a = fmaf(St[r][jj], Vs[jj][pd], a);
                oacc[ii] = a;
            }
        }
        __syncthreads();
    }
    if (tid < 192) {
#pragma unroll
        for (int ii = 0; ii < 16; ++ii) {
            int r = pg * 16 + ii;
            of[(nb + i0 + r) * kD + coff + pd] = oacc[ii] / lrow[r];
        }
    }
}

// ---------------- BatchNorm over node dim (batch stats, biased var) -------------
__global__ __launch_bounds__(384) void bn_stats(const float* __restrict__ A,
                                                float* __restrict__ stats)
{
    int c = threadIdx.x;
    int r0 = blockIdx.x * 128;
    float s = 0.f, s2 = 0.f;
    for (int r = 0; r < 128; ++r) {
        float v = A[(size_t)(r0 + r) * kD + c];
        s += v; s2 += v * v;
    }
    atomicAdd(&stats[c], s);
    atomicAdd(&stats[kD + c], s2);
}

__global__ __launch_bounds__(256) void bn_apply(
    const float* __restrict__ A, const float* __restrict__ stats,
    const float* __restrict__ g, const float* __restrict__ be,
    float* __restrict__ out)
{
    unsigned i = (blockIdx.x * 256u + threadIdx.x) * 4u;
    unsigned c = i % kD;            // 4 | 384 -> no row crossing
    float4 v = *reinterpret_cast<const float4*>(A + i);
    float r[4] = {v.x, v.y, v.z, v.w};
#pragma unroll
    for (int j = 0; j < 4; ++j) {
        float m  = stats[c + j] * (1.f / kN);
        float va = stats[kD + c + j] * (1.f / kN) - m * m;
        r[j] = (r[j] - m) * rsqrtf(va + 1e-5f) * g[c + j] + be[c + j];
    }
    float4 o; o.x = r[0]; o.y = r[1]; o.z = r[2]; o.w = r[3];
    *reinterpret_cast<float4*>(out + i) = o;
}

} // anonymous namespace

extern "C" void kernel_launch(void* const* d_in, const int* in_sizes, int n_in,
                              void* d_out, int out_size, void* d_ws, size_t ws_size,
                              hipStream_t stream)
{
    (void)in_sizes; (void)n_in; (void)out_size; (void)ws_size;
    const float* x    = (const float*)d_in[0];
    const int*   ei   = (const int*)d_in[1];
    const float* ea   = (const float*)d_in[2];
    // d_in[3] = batch_idx: provably arange(N)//S -> identity layout, unused
    const float* W1   = (const float*)d_in[4];
    const float* b1   = (const float*)d_in[5];
    const float* W2   = (const float*)d_in[6];
    const float* b2   = (const float*)d_in[7];
    const float* g1l  = (const float*)d_in[8];
    const float* be1l = (const float*)d_in[9];
    const float* Wq   = (const float*)d_in[10];
    const float* bq   = (const float*)d_in[11];
    const float* Wk   = (const float*)d_in[12];
    const float* bk   = (const float*)d_in[13];
    const float* Wv   = (const float*)d_in[14];
    const float* bv   = (const float*)d_in[15];
    const float* Wo   = (const float*)d_in[16];
    const float* bo   = (const float*)d_in[17];
    const float* g1a  = (const float*)d_in[18];
    const float* be1a = (const float*)d_in[19];
    const float* Wf1  = (const float*)d_in[20];
    const float* bf1  = (const float*)d_in[21];
    const float* Wf2  = (const float*)d_in[22];
    const float* bf2  = (const float*)d_in[23];
    const float* g2   = (const float*)d_in[24];
    const float* be2  = (const float*)d_in[25];

    float* out   = (float*)d_out;
    float* ws    = (float*)d_ws;
    float* stats = ws;            // 1024 f32 (uses 768)
    float* s0 = ws + 1024;        // ND
    float* s1 = s0 + kND;         // ND
    float* s3 = s1 + kND;         // 2*ND (ffn hidden / v)
    // d_out (ND f32) doubles as scratch: fully overwritten before final BN.

    dim3 blk(256);
    dim3 gD(kD / 64, kN / 64);    // (6, 512)
    dim3 gFF(kFF / 64, kN / 64);  // (12, 512)
    const int ew = kND / 1024;    // elementwise grid: 4 elems/thread

    // ---- local MPNN: GINEConv + MLP + residual + BN ----
    hipMemsetAsync(s0, 0, (size_t)kND * sizeof(float), stream);
    edge_kernel<<<kE * 96 / 256, blk, 0, stream>>>(x, ea, ei, s0);
    addf_kernel<<<ew, blk, 0, stream>>>(s0, x);                               // hl0 = x + agg
    gemm_kernel<true, 0><<<gD, blk, 0, stream>>>(s0, W1, b1, nullptr, s1, kN, kD, kD);
    gemm_kernel<false, 1><<<gD, blk, 0, stream>>>(s1, W2, b2, x, s0, kN, kD, kD);     // x + MLP
    hipMemsetAsync(stats, 0, 2 * kD * sizeof(float), stream);
    bn_stats<<<256, 384, 0, stream>>>(s0, stats);
    bn_apply<<<ew, blk, 0, stream>>>(s0, stats, g1l, be1l, s0);               // hl in s0

    // ---- global attention over x (dense batch == reshape, mask all-true) ----
    gemm_kernel<false, 0><<<gD, blk, 0, stream>>>(x, Wq, bq, nullptr, s1, kN, kD, kD);
    gemm_kernel<false, 0><<<gD, blk, 0, stream>>>(x, Wk, bk, nullptr, out, kN, kD, kD);
    gemm_kernel<false, 0><<<gD, blk, 0, stream>>>(x, Wv, bv, nullptr, s3, kN, kD, kD);
    attn_kernel<<<dim3(kS / 64, kB * kH), blk, 0, stream>>>(s1, out, s3, s1); // o over q
    gemm_kernel<false, 1><<<gD, blk, 0, stream>>>(s1, Wo, bo, x, out, kN, kD, kD);    // x + O@Wo
    hipMemsetAsync(stats, 0, 2 * kD * sizeof(float), stream);
    bn_stats<<<256, 384, 0, stream>>>(out, stats);
    bn_apply<<<ew, blk, 0, stream>>>(out, stats, g1a, be1a, out);             // ha in out

    // ---- combine + FFN + BN ----
    addf_kernel<<<ew, blk, 0, stream>>>(s0, out);                             // h = hl + ha (s0)
    gemm_kernel<true, 0><<<gFF, blk, 0, stream>>>(s0, Wf1, bf1, nullptr, s3, kN, kD, kFF);
    gemm_kernel<false, 1><<<gD, blk, 0, stream>>>(s3, Wf2, bf2, s0, out, kN, kFF, kD);
    hipMemsetAsync(stats, 0, 2 * kD * sizeof(float), stream);
    bn_stats<<<256, 384, 0, stream>>>(out, stats);
    bn_apply<<<ew, blk, 0, stream>>>(out, stats, g2, be2, out);
}